// Round 1
// 524.813 us; speedup vs baseline: 1.0099x; 1.0099x over previous
//
#include <hip/hip_runtime.h>
#include <hip/hip_bf16.h>

// Problem constants (match reference)
#define NN 100000     // nodes
#define NE 1600000    // edges
#define HD 128        // feature/hidden dim
#define NG 512        // graphs
#define BN_EPS 1e-5f
#define NXCD 8        // XCDs on MI355X (m09: HW_REG_XCC_ID returns 0-7)

#define GEMM_BLOCKS 1563          // ceil(NN/64)
#define HIST_BLOCKS 6250          // NE/256

typedef __attribute__((ext_vector_type(8))) short short8;
typedef __attribute__((ext_vector_type(4))) float floatx4;

// ---- bf16 helpers (RNE) ----
__device__ __forceinline__ ushort f2bf(float f) {
    union { float f; uint u; } v; v.f = f;
    uint r = (v.u + 0x7FFF + ((v.u >> 16) & 1)) >> 16;
    return (ushort)r;
}
__device__ __forceinline__ float bflo(uint u) { union { uint u; float f; } v; v.u = u << 16; return v.f; }
__device__ __forceinline__ float bfhi(uint u) { union { uint u; float f; } v; v.u = u & 0xFFFF0000u; return v.f; }

// ---- XCD id: HW_REG_XCC_ID = hwreg(id=20, offset=0, size=32) ----
// getreg imm encoding: id[5:0] | offset[10:6]<<6 | (size-1)[15:11]<<11
__device__ __forceinline__ uint xcc_id() {
    return (uint)__builtin_amdgcn_s_getreg(20 | (31 << 11)) & (NXCD - 1);
}

// ---------------- zero helper ----------------
__global__ void k_zero_i(int* p, int n) {
    int i = blockIdx.x * 256 + threadIdx.x;
    if (i < n) p[i] = 0;
}

// ---------------- W prep: Wt[n][k] = bf16(W[k][n]), 3 layers in one launch ----------------
__global__ void k_prep_w3(const float* __restrict__ W1, const float* __restrict__ W2,
                          const float* __restrict__ W3,
                          ushort* __restrict__ Wt1, ushort* __restrict__ Wt2,
                          ushort* __restrict__ Wt3) {
    int w = blockIdx.x >> 6;                       // 64 blocks per layer
    int i = (blockIdx.x & 63) * 256 + threadIdx.x; // 0..16383
    const float* W = (w == 0) ? W1 : (w == 1) ? W2 : W3;
    ushort* Wt = (w == 0) ? Wt1 : (w == 1) ? Wt2 : Wt3;
    int k = i >> 7, n = i & 127;
    Wt[n * 128 + k] = f2bf(W[i]);
}

// ---------------- fused: GEMM1 (fp32 x @ Wt1 -> unscaled bf16 hs)  ||  hist+rank ----------------
// hist now uses per-XCD private counters + XCD-local (workgroup-scope) atomics:
// every wave incrementing copy x runs on XCD x, so the atomic executes in the
// local TCC (cached) instead of the memory-side coherence point.
__launch_bounds__(256)
__global__ void k_fused1(const float* __restrict__ x, const ushort* __restrict__ Wt,
                         ushort* __restrict__ hs,
                         const int* __restrict__ dst, int* __restrict__ indeg,
                         int* __restrict__ rank) {
    const int tid = threadIdx.x;
    if (blockIdx.x >= GEMM_BLOCKS) {
        // ---- per-XCD histogram + per-edge local rank ----
        int e = (blockIdx.x - GEMM_BLOCKS) * 256 + tid;
        if (e < NE) {
            uint xc = xcc_id();
            int d = dst[e];
            int lr = __hip_atomic_fetch_add(&indeg[xc * NN + d], 1,
                                            __ATOMIC_RELAXED, __HIP_MEMORY_SCOPE_WORKGROUP);
            rank[e] = (int)((xc << 24) | (uint)lr);   // deg < 2^24 always
        }
        return;
    }
    // ---- GEMM role: 4 waves, 64 rows, B-frags straight from global (L1-resident 32 KB) ----
    const int wave = tid >> 6, lane = tid & 63;
    const int m = lane & 15, kg = lane >> 4;
    const long row0 = (long)blockIdx.x * 64 + wave * 16;

    long arow = row0 + m;
    long arc = arow < NN ? arow : (NN - 1);
    const float* xf = x + arc * 128;
    short8 a[4];
#pragma unroll
    for (int s = 0; s < 4; ++s) {
        float4 f0 = *(const float4*)(xf + s * 32 + kg * 8);
        float4 f1 = *(const float4*)(xf + s * 32 + kg * 8 + 4);
        short8 t;
        t[0] = (short)f2bf(f0.x); t[1] = (short)f2bf(f0.y);
        t[2] = (short)f2bf(f0.z); t[3] = (short)f2bf(f0.w);
        t[4] = (short)f2bf(f1.x); t[5] = (short)f2bf(f1.y);
        t[6] = (short)f2bf(f1.z); t[7] = (short)f2bf(f1.w);
        a[s] = t;
    }

    floatx4 acc[8];
#pragma unroll
    for (int ct = 0; ct < 8; ++ct) acc[ct] = (floatx4){0.f, 0.f, 0.f, 0.f};

#pragma unroll
    for (int s = 0; s < 4; ++s) {
#pragma unroll
        for (int ct = 0; ct < 8; ++ct) {
            short8 b = *(const short8*)(Wt + (ct * 16 + m) * 128 + s * 32 + kg * 8);
            acc[ct] = __builtin_amdgcn_mfma_f32_16x16x32_bf16(a[s], b, acc[ct], 0, 0, 0);
        }
    }

#pragma unroll
    for (int r = 0; r < 4; ++r) {
        long orow = row0 + kg * 4 + r;
        if (orow < NN) {
#pragma unroll
            for (int ct = 0; ct < 8; ++ct)
                hs[orow * 128 + ct * 16 + m] = f2bf(acc[ct][r]);   // unscaled
        }
    }
}

// ---------------- scan1 (sums 8 XCD copies) + dinv fused ----------------
__global__ void k_scan1d(const int* __restrict__ indeg, int* __restrict__ rs,
                         int* __restrict__ aux, float* __restrict__ dinv) {
    __shared__ int s[256];
    int t = threadIdx.x;
    int base = blockIdx.x * 1024 + t * 4;
    int v0 = 0, v1 = 0, v2 = 0, v3 = 0;
#pragma unroll
    for (int xc = 0; xc < NXCD; ++xc) {
        const int* p = indeg + xc * NN;
        if (base + 0 < NN) v0 += p[base + 0];
        if (base + 1 < NN) v1 += p[base + 1];
        if (base + 2 < NN) v2 += p[base + 2];
        if (base + 3 < NN) v3 += p[base + 3];
    }
    if (base + 0 < NN) dinv[base + 0] = rsqrtf((float)(v0 + 1));
    if (base + 1 < NN) dinv[base + 1] = rsqrtf((float)(v1 + 1));
    if (base + 2 < NN) dinv[base + 2] = rsqrtf((float)(v2 + 1));
    if (base + 3 < NN) dinv[base + 3] = rsqrtf((float)(v3 + 1));
    int tsum = v0 + v1 + v2 + v3;
    s[t] = tsum;
    __syncthreads();
    for (int o = 1; o < 256; o <<= 1) {
        int x = 0;
        if (t >= o) x = s[t - o];
        __syncthreads();
        s[t] += x;
        __syncthreads();
    }
    int excl = s[t] - tsum;
    if (base + 0 < NN) rs[base + 0] = excl;
    if (base + 1 < NN) rs[base + 1] = excl + v0;
    if (base + 2 < NN) rs[base + 2] = excl + v0 + v1;
    if (base + 3 < NN) rs[base + 3] = excl + v0 + v1 + v2;
    if (t == 255) aux[blockIdx.x] = s[255];
}

__global__ void k_scan2(int* __restrict__ aux, int nblk) {
    __shared__ int s[128];
    int t = threadIdx.x;
    int v = (t < nblk) ? aux[t] : 0;
    s[t] = v;
    __syncthreads();
    for (int o = 1; o < 128; o <<= 1) {
        int x = 0;
        if (t >= o) x = s[t - o];
        __syncthreads();
        s[t] += x;
        __syncthreads();
    }
    if (t < nblk) aux[t] = s[t] - v;
}

// finalize rs AND convert per-XCD counts into global exclusive bases
__global__ void k_scan3(int* __restrict__ rs, const int* __restrict__ aux,
                        int* __restrict__ indeg) {
    int i = blockIdx.x * 256 + threadIdx.x;
    if (i < NN) {
        int b = rs[i] + aux[i >> 10];
        rs[i] = b;
        int run = b;
#pragma unroll
        for (int xc = 0; xc < NXCD; ++xc) {
            int c = indeg[xc * NN + i];
            indeg[xc * NN + i] = run;   // becomes global base for (xcd, node)
            run += c;
        }
    }
    if (i == 0) rs[NN] = NE;
}

// ---------------- CSR fill (atomic-free; rank = packed xcd<<24 | local) ----------------
__global__ void k_fill(const int* __restrict__ src, const int* __restrict__ dst,
                       const int* __restrict__ rank, const int* __restrict__ indeg,
                       int* __restrict__ csr) {
    int e = blockIdx.x * 256 + threadIdx.x;
    if (e >= NE) return;
    uint r = (uint)rank[e];
    int xc = (int)(r >> 24);
    int lr = (int)(r & 0xFFFFFFu);
    csr[indeg[xc * NN + dst[e]] + lr] = src[e];
}

// ---------------- BN affine prep: 3 layers in one launch ----------------
__global__ void k_bn_prep3(const float* __restrict__ b1, const float* __restrict__ g1,
                           const float* __restrict__ be1, const float* __restrict__ m1,
                           const float* __restrict__ v1,
                           const float* __restrict__ b2, const float* __restrict__ g2,
                           const float* __restrict__ be2, const float* __restrict__ m2,
                           const float* __restrict__ v2,
                           const float* __restrict__ b3, const float* __restrict__ g3,
                           const float* __restrict__ be3, const float* __restrict__ m3,
                           const float* __restrict__ v3,
                           float* scale1, float* shift1, float* scale2, float* shift2,
                           float* scale3, float* shift3) {
    int l = blockIdx.x, f = threadIdx.x;
    const float *b, *g, *be, *m, *v;
    float *sc, *sh;
    if (l == 0)      { b = b1; g = g1; be = be1; m = m1; v = v1; sc = scale1; sh = shift1; }
    else if (l == 1) { b = b2; g = g2; be = be2; m = m2; v = v2; sc = scale2; sh = shift2; }
    else             { b = b3; g = g3; be = be3; m = m3; v = v3; sc = scale3; sh = shift3; }
    float s = g[f] * rsqrtf(v[f] + BN_EPS);
    sc[f] = s;
    sh[f] = (b[f] - m[f]) * s + be[f];
}

// ---------------- graph boundaries ----------------
__global__ void k_gstart(const int* __restrict__ batch, int* __restrict__ gstart) {
    int g = blockIdx.x * 256 + threadIdx.x;
    if (g > NG) return;
    if (g == NG) { gstart[NG] = NN; return; }
    int lo = 0, hi = NN;
    while (lo < hi) {
        int mid = (lo + hi) >> 1;
        if (batch[mid] < g) lo = mid + 1; else hi = mid;
    }
    gstart[g] = lo;
}

// ---------------- MFMA GEMM layers 2/3 (R4-proven: LDS-staged W, scaled epilogue) ----------------
#define WT_STRIDE 136
__launch_bounds__(256)
__global__ void k_gemm_l23(const ushort* __restrict__ xb, const ushort* __restrict__ Wt,
                           const float* __restrict__ dinv, ushort* __restrict__ hs) {
    __shared__ ushort sWt[128 * WT_STRIDE];
    const int tid = threadIdx.x;
    for (int i = tid; i < 2048; i += 256) {
        int row = i >> 4, seg = i & 15;
        *(uint4*)&sWt[row * WT_STRIDE + seg * 8] = *(const uint4*)(Wt + row * 128 + seg * 8);
    }
    __syncthreads();

    const int wave = tid >> 6, lane = tid & 63;
    const int m = lane & 15, kg = lane >> 4;
    const long row0 = (long)blockIdx.x * 64 + wave * 16;

    long arow = row0 + m;
    long arc = arow < NN ? arow : (NN - 1);
    short8 a[4];
#pragma unroll
    for (int s = 0; s < 4; ++s)
        a[s] = *(const short8*)(xb + arc * 128 + s * 32 + kg * 8);

    floatx4 acc[8];
#pragma unroll
    for (int ct = 0; ct < 8; ++ct) acc[ct] = (floatx4){0.f, 0.f, 0.f, 0.f};

#pragma unroll
    for (int s = 0; s < 4; ++s) {
#pragma unroll
        for (int ct = 0; ct < 8; ++ct) {
            short8 b = *(const short8*)&sWt[(ct * 16 + m) * WT_STRIDE + s * 32 + kg * 8];
            acc[ct] = __builtin_amdgcn_mfma_f32_16x16x32_bf16(a[s], b, acc[ct], 0, 0, 0);
        }
    }

#pragma unroll
    for (int r = 0; r < 4; ++r) {
        long orow = row0 + kg * 4 + r;
        if (orow < NN) {
            float dd = dinv[orow];
#pragma unroll
            for (int ct = 0; ct < 8; ++ct)
                hs[orow * 128 + ct * 16 + m] = f2bf(acc[ct][r] * dd);
        }
    }
}

// ---------------- gather + BN + ReLU fused: ONE WAVE PER NODE ----------------
// lane = (sub, c): sub = lane>>4 is one of 4 parallel edge slots, c = lane&15 is
// the 8-feature column segment. Uniform loop bounds across the wave (no
// divergence between nodes), 2 gathers in flight per lane, csr indices
// prefetched one iteration ahead. Final 2-step shfl_xor reduction over subs.
template <bool SCALE_SRC>
__launch_bounds__(256)
__global__ void k_gather_w(const ushort* __restrict__ hs, const int* __restrict__ rs,
                           const int* __restrict__ csr, const float* __restrict__ dinv,
                           const float* __restrict__ scale, const float* __restrict__ shift,
                           ushort* __restrict__ xout) {
    const int tid = threadIdx.x;
    const int d = blockIdx.x * 4 + (tid >> 6);     // one wave per node; grid = NN/4 exact
    const int lane = tid & 63;
    const int sub = lane >> 4;
    const int c0 = (lane & 15) * 8;

    const int e0 = rs[d], e1 = rs[d + 1];
    const float dd = dinv[d];

    float a0 = 0.f, a1 = 0.f, a2 = 0.f, a3 = 0.f,
          a4 = 0.f, a5 = 0.f, a6 = 0.f, a7 = 0.f;

    if (sub == 0) {   // self-loop term
        uint4 sv = *(const uint4*)(hs + (long)d * 128 + c0);
        float w = SCALE_SRC ? dd : 1.0f;
        a0 = w * bflo(sv.x); a1 = w * bfhi(sv.x);
        a2 = w * bflo(sv.y); a3 = w * bfhi(sv.y);
        a4 = w * bflo(sv.z); a5 = w * bfhi(sv.z);
        a6 = w * bflo(sv.w); a7 = w * bfhi(sv.w);
    }

    // sub s covers residues {s, s+4} mod 8 of [e0, e1): pairs (j, j+4), j += 8,
    // then at most one single. Indices for the next pair prefetched ahead.
    int j = e0 + sub;
    int s0 = 0, s1 = 0;
    bool have = (j < e1 - 4);
    if (have) { s0 = csr[j]; s1 = csr[j + 4]; }
    while (have) {
        int jn = j + 8;
        bool nxt = (jn < e1 - 4);
        int n0 = 0, n1 = 0;
        if (nxt) { n0 = csr[jn]; n1 = csr[jn + 4]; }
        float w0 = SCALE_SRC ? dinv[s0] : 1.0f;
        float w1 = SCALE_SRC ? dinv[s1] : 1.0f;
        uint4 v0 = *(const uint4*)(hs + (long)s0 * 128 + c0);
        uint4 v1 = *(const uint4*)(hs + (long)s1 * 128 + c0);
        a0 += w0 * bflo(v0.x) + w1 * bflo(v1.x);
        a1 += w0 * bfhi(v0.x) + w1 * bfhi(v1.x);
        a2 += w0 * bflo(v0.y) + w1 * bflo(v1.y);
        a3 += w0 * bfhi(v0.y) + w1 * bfhi(v1.y);
        a4 += w0 * bflo(v0.z) + w1 * bflo(v1.z);
        a5 += w0 * bfhi(v0.z) + w1 * bfhi(v1.z);
        a6 += w0 * bflo(v0.w) + w1 * bflo(v1.w);
        a7 += w0 * bfhi(v0.w) + w1 * bfhi(v1.w);
        j = jn; s0 = n0; s1 = n1; have = nxt;
    }
    if (j < e1) {
        int sx = csr[j];
        float wx = SCALE_SRC ? dinv[sx] : 1.0f;
        uint4 v0 = *(const uint4*)(hs + (long)sx * 128 + c0);
        a0 += wx * bflo(v0.x); a1 += wx * bfhi(v0.x);
        a2 += wx * bflo(v0.y); a3 += wx * bfhi(v0.y);
        a4 += wx * bflo(v0.z); a5 += wx * bfhi(v0.z);
        a6 += wx * bflo(v0.w); a7 += wx * bfhi(v0.w);
    }

    // reduce across the 4 edge slots (lanes differing in bits 4,5)
    a0 += __shfl_xor(a0, 16); a1 += __shfl_xor(a1, 16);
    a2 += __shfl_xor(a2, 16); a3 += __shfl_xor(a3, 16);
    a4 += __shfl_xor(a4, 16); a5 += __shfl_xor(a5, 16);
    a6 += __shfl_xor(a6, 16); a7 += __shfl_xor(a7, 16);
    a0 += __shfl_xor(a0, 32); a1 += __shfl_xor(a1, 32);
    a2 += __shfl_xor(a2, 32); a3 += __shfl_xor(a3, 32);
    a4 += __shfl_xor(a4, 32); a5 += __shfl_xor(a5, 32);
    a6 += __shfl_xor(a6, 32); a7 += __shfl_xor(a7, 32);

    if (sub == 0) {
        float4 sca = *(const float4*)(scale + c0);
        float4 scb = *(const float4*)(scale + c0 + 4);
        float4 sha = *(const float4*)(shift + c0);
        float4 shb = *(const float4*)(shift + c0 + 4);
        float r0 = fmaxf(dd * a0 * sca.x + sha.x, 0.f);
        float r1 = fmaxf(dd * a1 * sca.y + sha.y, 0.f);
        float r2 = fmaxf(dd * a2 * sca.z + sha.z, 0.f);
        float r3 = fmaxf(dd * a3 * sca.w + sha.w, 0.f);
        float r4 = fmaxf(dd * a4 * scb.x + shb.x, 0.f);
        float r5 = fmaxf(dd * a5 * scb.y + shb.y, 0.f);
        float r6 = fmaxf(dd * a6 * scb.z + shb.z, 0.f);
        float r7 = fmaxf(dd * a7 * scb.w + shb.w, 0.f);
        uint4 o;
        o.x = (uint)f2bf(r0) | ((uint)f2bf(r1) << 16);
        o.y = (uint)f2bf(r2) | ((uint)f2bf(r3) << 16);
        o.z = (uint)f2bf(r4) | ((uint)f2bf(r5) << 16);
        o.w = (uint)f2bf(r6) | ((uint)f2bf(r7) << 16);
        *(uint4*)(xout + (long)d * 128 + c0) = o;
    }
}

// ---------------- fused mean-pool + final linear ----------------
__global__ void k_pool_final2(const ushort* __restrict__ x, const int* __restrict__ gstart,
                              const float* __restrict__ Wl, const float* __restrict__ bl,
                              float* __restrict__ out) {
    __shared__ float red[256];
    int g = blockIdx.x;
    int tid = threadIdx.x;
    int f = tid & 127;
    int half = tid >> 7;
    int i0 = gstart[g], i1 = gstart[g + 1];

    float acc = 0.f;
    for (int i = i0 + half; i < i1; i += 2) {
        union { uint u; float f; } v; v.u = (uint)x[(long)i * 128 + f] << 16;
        acc += v.f;
    }
    red[tid] = acc;
    __syncthreads();
    if (tid < 128) red[tid] = (red[tid] + red[tid + 128]) * Wl[tid];
    __syncthreads();
    for (int o = 64; o > 0; o >>= 1) {
        if (tid < o) red[tid] += red[tid + o];
        __syncthreads();
    }
    if (tid == 0) out[g] = red[0] / fmaxf((float)(i1 - i0), 1.f) + bl[0];
}

// ---------------- launch ----------------
extern "C" void kernel_launch(void* const* d_in, const int* in_sizes, int n_in,
                              void* d_out, int out_size, void* d_ws, size_t ws_size,
                              hipStream_t stream) {
    const float* x   = (const float*)d_in[0];
    const int*   ei  = (const int*)d_in[1];
    const int*   bat = (const int*)d_in[2];
    const float* W1  = (const float*)d_in[3];
    const float* b1  = (const float*)d_in[4];
    const float* g1  = (const float*)d_in[5];
    const float* be1 = (const float*)d_in[6];
    const float* m1  = (const float*)d_in[7];
    const float* v1  = (const float*)d_in[8];
    const float* W2  = (const float*)d_in[9];
    const float* b2  = (const float*)d_in[10];
    const float* g2  = (const float*)d_in[11];
    const float* be2 = (const float*)d_in[12];
    const float* m2  = (const float*)d_in[13];
    const float* v2  = (const float*)d_in[14];
    const float* W3  = (const float*)d_in[15];
    const float* b3  = (const float*)d_in[16];
    const float* g3  = (const float*)d_in[17];
    const float* be3 = (const float*)d_in[18];
    const float* m3  = (const float*)d_in[19];
    const float* v3  = (const float*)d_in[20];
    const float* Wl  = (const float*)d_in[21];
    const float* bl  = (const float*)d_in[22];
    float* out = (float*)d_out;

    const int* srcp = ei;        // edge_index[0]
    const int* dstp = ei + NE;   // edge_index[1]

    // ---- workspace layout ----
    char* ws = (char*)d_ws;
    size_t off = 0;
    auto alloc = [&](size_t bytes) { char* p = ws + off; off += (bytes + 255) & ~255ULL; return p; };
    float*  dinv   = (float*) alloc(NN * 4);
    int*    indeg  = (int*)   alloc((size_t)NXCD * NN * 4);   // 8 XCD-private copies, 3.2 MB
    int*    rs     = (int*)   alloc((NN + 1) * 4);
    int*    aux    = (int*)   alloc(128 * 4);
    int*    csr    = (int*)   alloc(NE * 4);           // 6.4 MB
    int*    rank   = (int*)   alloc(NE * 4);           // 6.4 MB
    float*  scale1 = (float*) alloc(HD * 4);
    float*  shift1 = (float*) alloc(HD * 4);
    float*  scale2 = (float*) alloc(HD * 4);
    float*  shift2 = (float*) alloc(HD * 4);
    float*  scale3 = (float*) alloc(HD * 4);
    float*  shift3 = (float*) alloc(HD * 4);
    int*    gstart = (int*)   alloc((NG + 1) * 4);
    ushort* Wt1    = (ushort*)alloc(128 * 128 * 2);    // 32 KB
    ushort* Wt2    = (ushort*)alloc(128 * 128 * 2);
    ushort* Wt3    = (ushort*)alloc(128 * 128 * 2);
    ushort* hs     = (ushort*)alloc((size_t)NN * HD * 2);   // 25.6 MB
    ushort* xbuf   = (ushort*)alloc((size_t)NN * HD * 2);   // 25.6 MB

    const int nblk_scan = (NN + 1023) / 1024;   // 98
    const int grid_n    = (NN + 255) / 256;
    const int grid_e    = (NE + 255) / 256;     // 6250
    const int gath_grid = NN / 4;               // 25000 (one wave per node, exact)

    // ---- prep (independent of edges) ----
    k_zero_i<<<(NXCD * NN + 255) / 256, 256, 0, stream>>>(indeg, NXCD * NN);
    k_prep_w3<<<192, 256, 0, stream>>>(W1, W2, W3, Wt1, Wt2, Wt3);

    // ---- fused: GEMM1 (unscaled) || per-XCD hist+rank ----
    k_fused1<<<GEMM_BLOCKS + HIST_BLOCKS, 256, 0, stream>>>(x, Wt1, hs, dstp, indeg, rank);

    // ---- CSR: scan (+dinv), per-XCD base conversion, fill ----
    k_scan1d<<<nblk_scan, 256, 0, stream>>>(indeg, rs, aux, dinv);
    k_scan2<<<1, 128, 0, stream>>>(aux, nblk_scan);
    k_scan3<<<grid_n, 256, 0, stream>>>(rs, aux, indeg);
    k_fill<<<grid_e, 256, 0, stream>>>(srcp, dstp, rank, indeg, csr);

    // ---- BN prep + graph boundaries ----
    k_bn_prep3<<<3, 128, 0, stream>>>(b1, g1, be1, m1, v1, b2, g2, be2, m2, v2,
                                      b3, g3, be3, m3, v3,
                                      scale1, shift1, scale2, shift2, scale3, shift3);
    k_gstart<<<3, 256, 0, stream>>>(bat, gstart);

    // ---- layer 1 gather (applies dinv[s] and dinv[d]) ----
    k_gather_w<true><<<gath_grid, 256, 0, stream>>>(hs, rs, csr, dinv, scale1, shift1, xbuf);
    // ---- layer 2 ----
    k_gemm_l23<<<GEMM_BLOCKS, 256, 0, stream>>>(xbuf, Wt2, dinv, hs);
    k_gather_w<false><<<gath_grid, 256, 0, stream>>>(hs, rs, csr, dinv, scale2, shift2, xbuf);
    // ---- layer 3 ----
    k_gemm_l23<<<GEMM_BLOCKS, 256, 0, stream>>>(xbuf, Wt3, dinv, hs);
    k_gather_w<false><<<gath_grid, 256, 0, stream>>>(hs, rs, csr, dinv, scale3, shift3, xbuf);

    // ---- pool + final ----
    k_pool_final2<<<NG, 256, 0, stream>>>(xbuf, gstart, Wl, bl, out);
}

// Round 2
// 505.581 us; speedup vs baseline: 1.0483x; 1.0380x over previous
//
#include <hip/hip_runtime.h>
#include <hip/hip_bf16.h>

// Problem constants (match reference)
#define NN 100000     // nodes
#define NE 1600000    // edges
#define HD 128        // feature/hidden dim
#define NG 512        // graphs
#define BN_EPS 1e-5f

#define GEMM_BLOCKS 1563          // ceil(NN/64)

// ---- bin-sort CSR build params ----
#define BIN_SHIFT 8
#define NBIN 391                  // ceil(NN/256)
#define TILE 16384                // edges per binning block
#define NBLK_BIN 98               // ceil(NE/TILE)

typedef __attribute__((ext_vector_type(8))) short short8;
typedef __attribute__((ext_vector_type(4))) float floatx4;

// ---- bf16 helpers (RNE) ----
__device__ __forceinline__ ushort f2bf(float f) {
    union { float f; uint u; } v; v.f = f;
    uint r = (v.u + 0x7FFF + ((v.u >> 16) & 1)) >> 16;
    return (ushort)r;
}
__device__ __forceinline__ float bflo(uint u) { union { uint u; float f; } v; v.u = u << 16; return v.f; }
__device__ __forceinline__ float bfhi(uint u) { union { uint u; float f; } v; v.u = u & 0xFFFF0000u; return v.f; }

// ---------------- fused prep: W transpose (blk<192) | BN affine (192-194) | graph counts (195-196) ----------------
__global__ void k_prep_all(const float* __restrict__ W1, const float* __restrict__ W2,
                           const float* __restrict__ W3,
                           ushort* __restrict__ Wt1, ushort* __restrict__ Wt2,
                           ushort* __restrict__ Wt3,
                           const float* __restrict__ b1, const float* __restrict__ g1,
                           const float* __restrict__ be1, const float* __restrict__ m1,
                           const float* __restrict__ v1,
                           const float* __restrict__ b2, const float* __restrict__ g2,
                           const float* __restrict__ be2, const float* __restrict__ m2,
                           const float* __restrict__ v2,
                           const float* __restrict__ b3, const float* __restrict__ g3,
                           const float* __restrict__ be3, const float* __restrict__ m3,
                           const float* __restrict__ v3,
                           float* scale1, float* shift1, float* scale2, float* shift2,
                           float* scale3, float* shift3,
                           const int* __restrict__ bat, float* __restrict__ invcnt,
                           float* __restrict__ out2d) {
    int blk = blockIdx.x, tid = threadIdx.x;
    if (blk < 192) {
        int w = blk >> 6;
        int i = (blk & 63) * 256 + tid;
        const float* W = (w == 0) ? W1 : (w == 1) ? W2 : W3;
        ushort* Wt = (w == 0) ? Wt1 : (w == 1) ? Wt2 : Wt3;
        int k = i >> 7, n = i & 127;
        Wt[n * 128 + k] = f2bf(W[i]);
    } else if (blk < 195) {
        if (tid < 128) {
            int l = blk - 192;
            const float *b, *g, *be, *m, *v;
            float *sc, *sh;
            if (l == 0)      { b = b1; g = g1; be = be1; m = m1; v = v1; sc = scale1; sh = shift1; }
            else if (l == 1) { b = b2; g = g2; be = be2; m = m2; v = v2; sc = scale2; sh = shift2; }
            else             { b = b3; g = g3; be = be3; m = m3; v = v3; sc = scale3; sh = shift3; }
            float s = g[tid] * rsqrtf(v[tid] + BN_EPS);
            sc[tid] = s;
            sh[tid] = (b[tid] - m[tid]) * s + be[tid];
        }
    } else {
        int g = (blk - 195) * 256 + tid;
        if (g < NG) {
            int lo = 0, hi = NN;
            while (lo < hi) { int mid = (lo + hi) >> 1; if (bat[mid] < g) lo = mid + 1; else hi = mid; }
            int lo2 = lo, hi2 = NN;
            while (lo2 < hi2) { int mid = (lo2 + hi2) >> 1; if (bat[mid] < g + 1) lo2 = mid + 1; else hi2 = mid; }
            int cnt = lo2 - lo;
            invcnt[g] = 1.f / fmaxf((float)cnt, 1.f);
#pragma unroll
            for (int i = 0; i < 8; ++i) out2d[g * 8 + i] = 0.f;
        }
    }
}

// ---------------- fused: GEMM1 (fp32 x @ Wt1 -> unscaled bf16 hs)  ||  bin histogram (LDS, no global atomics) ----------------
__launch_bounds__(256)
__global__ void k_fused1(const float* __restrict__ x, const ushort* __restrict__ Wt,
                         ushort* __restrict__ hs,
                         const int* __restrict__ dst, int* __restrict__ L) {
    __shared__ int lh[NBIN];
    const int tid = threadIdx.x;
    if (blockIdx.x >= GEMM_BLOCKS) {
        // ---- bin histogram role: 98 blocks, 16384 edges each ----
        int blk = blockIdx.x - GEMM_BLOCKS;
        for (int i = tid; i < NBIN; i += 256) lh[i] = 0;
        __syncthreads();
        long base = (long)blk * TILE;
#pragma unroll 4
        for (int i = 0; i < TILE / 256; ++i) {
            long e = base + i * 256 + tid;
            if (e < NE) atomicAdd(&lh[dst[e] >> BIN_SHIFT], 1);
        }
        __syncthreads();
        for (int i = tid; i < NBIN; i += 256) L[i * NBLK_BIN + blk] = lh[i];
        return;
    }
    // ---- GEMM role: 4 waves, 64 rows, B-frags straight from global (L1-resident 32 KB) ----
    const int wave = tid >> 6, lane = tid & 63;
    const int m = lane & 15, kg = lane >> 4;
    const long row0 = (long)blockIdx.x * 64 + wave * 16;

    long arow = row0 + m;
    long arc = arow < NN ? arow : (NN - 1);
    const float* xf = x + arc * 128;
    short8 a[4];
#pragma unroll
    for (int s = 0; s < 4; ++s) {
        float4 f0 = *(const float4*)(xf + s * 32 + kg * 8);
        float4 f1 = *(const float4*)(xf + s * 32 + kg * 8 + 4);
        short8 t;
        t[0] = (short)f2bf(f0.x); t[1] = (short)f2bf(f0.y);
        t[2] = (short)f2bf(f0.z); t[3] = (short)f2bf(f0.w);
        t[4] = (short)f2bf(f1.x); t[5] = (short)f2bf(f1.y);
        t[6] = (short)f2bf(f1.z); t[7] = (short)f2bf(f1.w);
        a[s] = t;
    }

    floatx4 acc[8];
#pragma unroll
    for (int ct = 0; ct < 8; ++ct) acc[ct] = (floatx4){0.f, 0.f, 0.f, 0.f};

#pragma unroll
    for (int s = 0; s < 4; ++s) {
#pragma unroll
        for (int ct = 0; ct < 8; ++ct) {
            short8 b = *(const short8*)(Wt + (ct * 16 + m) * 128 + s * 32 + kg * 8);
            acc[ct] = __builtin_amdgcn_mfma_f32_16x16x32_bf16(a[s], b, acc[ct], 0, 0, 0);
        }
    }

#pragma unroll
    for (int r = 0; r < 4; ++r) {
        long orow = row0 + kg * 4 + r;
        if (orow < NN) {
#pragma unroll
            for (int ct = 0; ct < 8; ++ct)
                hs[orow * 128 + ct * 16 + m] = f2bf(acc[ct][r]);   // unscaled
        }
    }
}

// ---------------- B: scan block-bin table -> absolute offsets; bin edge bases ----------------
__global__ void k_binscan(int* __restrict__ L, int* __restrict__ bin_ebase,
                          int* __restrict__ rs) {
    __shared__ int s[512];
    int t = threadIdx.x;   // 512 threads
    int tot = 0;
    if (t < NBIN) {
        int run = 0;
        for (int b = 0; b < NBLK_BIN; ++b) {
            int h = L[t * NBLK_BIN + b];
            L[t * NBLK_BIN + b] = run;      // exclusive within column
            run += h;
        }
        tot = run;
    }
    s[t] = tot;
    __syncthreads();
    for (int o = 1; o < 512; o <<= 1) {
        int x = (t >= o) ? s[t - o] : 0;
        __syncthreads();
        s[t] += x;
        __syncthreads();
    }
    int excl = s[t] - tot;
    if (t < NBIN) {
        bin_ebase[t] = excl;
        for (int b = 0; b < NBLK_BIN; ++b) L[t * NBLK_BIN + b] += excl;
    }
    if (t == 0) { bin_ebase[NBIN] = NE; rs[NN] = NE; }
}

// ---------------- C: scatter edges into bin-grouped order (LDS cursors only) ----------------
__launch_bounds__(256)
__global__ void k_binscatter(const int* __restrict__ src, const int* __restrict__ dst,
                             const int* __restrict__ L, uint* __restrict__ bpack) {
    __shared__ int off[NBIN];
    int t = threadIdx.x, blk = blockIdx.x;
    for (int i = t; i < NBIN; i += 256) off[i] = L[i * NBLK_BIN + blk];
    __syncthreads();
    long base = (long)blk * TILE;
#pragma unroll 4
    for (int i = 0; i < TILE / 256; ++i) {
        long e = base + i * 256 + t;
        if (e < NE) {
            int d = dst[e];
            int p = atomicAdd(&off[d >> BIN_SHIFT], 1);
            bpack[p] = (uint)src[e] | ((uint)(d & 255) << 24);   // src<2^17, local node in top 8
        }
    }
}

// ---------------- D: per-bin exact CSR + rs + dinv (all LDS) ----------------
__launch_bounds__(256)
__global__ void k_bincsr(const uint* __restrict__ bpack, const int* __restrict__ bin_ebase,
                         int* __restrict__ rs, float* __restrict__ dinv,
                         int* __restrict__ csr) {
    __shared__ int cnt[256];
    __shared__ int sc[256];
    __shared__ int run[256];
    int t = threadIdx.x, b = blockIdx.x;
    int e0 = bin_ebase[b], e1 = bin_ebase[b + 1];
    cnt[t] = 0;
    __syncthreads();
    for (int e = e0 + t; e < e1; e += 256) atomicAdd(&cnt[bpack[e] >> 24], 1);
    __syncthreads();
    int c = cnt[t];
    sc[t] = c;
    __syncthreads();
    for (int o = 1; o < 256; o <<= 1) {
        int x = (t >= o) ? sc[t - o] : 0;
        __syncthreads();
        sc[t] += x;
        __syncthreads();
    }
    int excl = sc[t] - c;
    int node = (b << BIN_SHIFT) + t;
    if (node < NN) {
        rs[node] = e0 + excl;
        dinv[node] = rsqrtf((float)(c + 1));   // +1 self-loop
    }
    run[t] = e0 + excl;
    __syncthreads();
    for (int e = e0 + t; e < e1; e += 256) {
        uint u = bpack[e];
        int p = atomicAdd(&run[u >> 24], 1);
        csr[p] = (int)(u & 0xFFFFFFu);
    }
}

// ---------------- MFMA GEMM layers 2/3 (LDS-staged W, scaled epilogue) ----------------
#define WT_STRIDE 136
__launch_bounds__(256)
__global__ void k_gemm_l23(const ushort* __restrict__ xb, const ushort* __restrict__ Wt,
                           const float* __restrict__ dinv, ushort* __restrict__ hs) {
    __shared__ ushort sWt[128 * WT_STRIDE];
    const int tid = threadIdx.x;
    for (int i = tid; i < 2048; i += 256) {
        int row = i >> 4, seg = i & 15;
        *(uint4*)&sWt[row * WT_STRIDE + seg * 8] = *(const uint4*)(Wt + row * 128 + seg * 8);
    }
    __syncthreads();

    const int wave = tid >> 6, lane = tid & 63;
    const int m = lane & 15, kg = lane >> 4;
    const long row0 = (long)blockIdx.x * 64 + wave * 16;

    long arow = row0 + m;
    long arc = arow < NN ? arow : (NN - 1);
    short8 a[4];
#pragma unroll
    for (int s = 0; s < 4; ++s)
        a[s] = *(const short8*)(xb + arc * 128 + s * 32 + kg * 8);

    floatx4 acc[8];
#pragma unroll
    for (int ct = 0; ct < 8; ++ct) acc[ct] = (floatx4){0.f, 0.f, 0.f, 0.f};

#pragma unroll
    for (int s = 0; s < 4; ++s) {
#pragma unroll
        for (int ct = 0; ct < 8; ++ct) {
            short8 b = *(const short8*)&sWt[(ct * 16 + m) * WT_STRIDE + s * 32 + kg * 8];
            acc[ct] = __builtin_amdgcn_mfma_f32_16x16x32_bf16(a[s], b, acc[ct], 0, 0, 0);
        }
    }

#pragma unroll
    for (int r = 0; r < 4; ++r) {
        long orow = row0 + kg * 4 + r;
        if (orow < NN) {
            float dd = dinv[orow];
#pragma unroll
            for (int ct = 0; ct < 8; ++ct)
                hs[orow * 128 + ct * 16 + m] = f2bf(acc[ct][r] * dd);
        }
    }
}

// ---------------- gather + BN + ReLU fused: ONE WAVE PER NODE ----------------
// POOL=true (layer 3): instead of writing xout, dot with Wl in-register and
// one fp32 atomic per node into 8-way-slotted per-graph accumulators.
template <bool SCALE_SRC, bool POOL>
__launch_bounds__(256)
__global__ void k_gather_w(const ushort* __restrict__ hs, const int* __restrict__ rs,
                           const int* __restrict__ csr, const float* __restrict__ dinv,
                           const float* __restrict__ scale, const float* __restrict__ shift,
                           ushort* __restrict__ xout,
                           const int* __restrict__ bat, const float* __restrict__ invcnt,
                           const float* __restrict__ Wl, float* __restrict__ out2d) {
    const int tid = threadIdx.x;
    const int d = blockIdx.x * 4 + (tid >> 6);     // one wave per node; grid = NN/4 exact
    const int lane = tid & 63;
    const int sub = lane >> 4;
    const int c0 = (lane & 15) * 8;

    const int e0 = rs[d], e1 = rs[d + 1];
    const float dd = dinv[d];

    float a0 = 0.f, a1 = 0.f, a2 = 0.f, a3 = 0.f,
          a4 = 0.f, a5 = 0.f, a6 = 0.f, a7 = 0.f;

    if (sub == 0) {   // self-loop term
        uint4 sv = *(const uint4*)(hs + (long)d * 128 + c0);
        float w = SCALE_SRC ? dd : 1.0f;
        a0 = w * bflo(sv.x); a1 = w * bfhi(sv.x);
        a2 = w * bflo(sv.y); a3 = w * bfhi(sv.y);
        a4 = w * bflo(sv.z); a5 = w * bfhi(sv.z);
        a6 = w * bflo(sv.w); a7 = w * bfhi(sv.w);
    }

    // sub s covers residues {s, s+4} mod 8 of [e0, e1): pairs (j, j+4), j += 8,
    // then at most one single. Indices for the next pair prefetched ahead.
    int j = e0 + sub;
    int s0 = 0, s1 = 0;
    bool have = (j < e1 - 4);
    if (have) { s0 = csr[j]; s1 = csr[j + 4]; }
    while (have) {
        int jn = j + 8;
        bool nxt = (jn < e1 - 4);
        int n0 = 0, n1 = 0;
        if (nxt) { n0 = csr[jn]; n1 = csr[jn + 4]; }
        float w0 = SCALE_SRC ? dinv[s0] : 1.0f;
        float w1 = SCALE_SRC ? dinv[s1] : 1.0f;
        uint4 v0 = *(const uint4*)(hs + (long)s0 * 128 + c0);
        uint4 v1 = *(const uint4*)(hs + (long)s1 * 128 + c0);
        a0 += w0 * bflo(v0.x) + w1 * bflo(v1.x);
        a1 += w0 * bfhi(v0.x) + w1 * bfhi(v1.x);
        a2 += w0 * bflo(v0.y) + w1 * bflo(v1.y);
        a3 += w0 * bfhi(v0.y) + w1 * bfhi(v1.y);
        a4 += w0 * bflo(v0.z) + w1 * bflo(v1.z);
        a5 += w0 * bfhi(v0.z) + w1 * bfhi(v1.z);
        a6 += w0 * bflo(v0.w) + w1 * bflo(v1.w);
        a7 += w0 * bfhi(v0.w) + w1 * bfhi(v1.w);
        j = jn; s0 = n0; s1 = n1; have = nxt;
    }
    if (j < e1) {
        int sx = csr[j];
        float wx = SCALE_SRC ? dinv[sx] : 1.0f;
        uint4 v0 = *(const uint4*)(hs + (long)sx * 128 + c0);
        a0 += wx * bflo(v0.x); a1 += wx * bfhi(v0.x);
        a2 += wx * bflo(v0.y); a3 += wx * bfhi(v0.y);
        a4 += wx * bflo(v0.z); a5 += wx * bfhi(v0.z);
        a6 += wx * bflo(v0.w); a7 += wx * bfhi(v0.w);
    }

    // reduce across the 4 edge slots (lanes differing in bits 4,5)
    a0 += __shfl_xor(a0, 16); a1 += __shfl_xor(a1, 16);
    a2 += __shfl_xor(a2, 16); a3 += __shfl_xor(a3, 16);
    a4 += __shfl_xor(a4, 16); a5 += __shfl_xor(a5, 16);
    a6 += __shfl_xor(a6, 16); a7 += __shfl_xor(a7, 16);
    a0 += __shfl_xor(a0, 32); a1 += __shfl_xor(a1, 32);
    a2 += __shfl_xor(a2, 32); a3 += __shfl_xor(a3, 32);
    a4 += __shfl_xor(a4, 32); a5 += __shfl_xor(a5, 32);
    a6 += __shfl_xor(a6, 32); a7 += __shfl_xor(a7, 32);

    float pd = 0.f;
    if (sub == 0) {
        float4 sca = *(const float4*)(scale + c0);
        float4 scb = *(const float4*)(scale + c0 + 4);
        float4 sha = *(const float4*)(shift + c0);
        float4 shb = *(const float4*)(shift + c0 + 4);
        float r0 = fmaxf(dd * a0 * sca.x + sha.x, 0.f);
        float r1 = fmaxf(dd * a1 * sca.y + sha.y, 0.f);
        float r2 = fmaxf(dd * a2 * sca.z + sha.z, 0.f);
        float r3 = fmaxf(dd * a3 * sca.w + sha.w, 0.f);
        float r4 = fmaxf(dd * a4 * scb.x + shb.x, 0.f);
        float r5 = fmaxf(dd * a5 * scb.y + shb.y, 0.f);
        float r6 = fmaxf(dd * a6 * scb.z + shb.z, 0.f);
        float r7 = fmaxf(dd * a7 * scb.w + shb.w, 0.f);
        if constexpr (POOL) {
            float4 wa = *(const float4*)(Wl + c0);
            float4 wb = *(const float4*)(Wl + c0 + 4);
            pd = r0 * wa.x + r1 * wa.y + r2 * wa.z + r3 * wa.w +
                 r4 * wb.x + r5 * wb.y + r6 * wb.z + r7 * wb.w;
        } else {
            uint4 o;
            o.x = (uint)f2bf(r0) | ((uint)f2bf(r1) << 16);
            o.y = (uint)f2bf(r2) | ((uint)f2bf(r3) << 16);
            o.z = (uint)f2bf(r4) | ((uint)f2bf(r5) << 16);
            o.w = (uint)f2bf(r6) | ((uint)f2bf(r7) << 16);
            *(uint4*)(xout + (long)d * 128 + c0) = o;
        }
    }
    if constexpr (POOL) {
        pd += __shfl_xor(pd, 1);
        pd += __shfl_xor(pd, 2);
        pd += __shfl_xor(pd, 4);
        pd += __shfl_xor(pd, 8);
        if (lane == 0) {
            int g = bat[d];
            atomicAdd(&out2d[g * 8 + (d & 7)], pd * invcnt[g]);
        }
    }
}

// ---------------- finalize: out[g] = bl + sum of 8 slots ----------------
__global__ void k_final(const float* __restrict__ out2d, const float* __restrict__ bl,
                        float* __restrict__ out) {
    int g = blockIdx.x * 256 + threadIdx.x;
    if (g >= NG) return;
    float s = bl[0];
#pragma unroll
    for (int i = 0; i < 8; ++i) s += out2d[g * 8 + i];
    out[g] = s;
}

// ---------------- launch ----------------
extern "C" void kernel_launch(void* const* d_in, const int* in_sizes, int n_in,
                              void* d_out, int out_size, void* d_ws, size_t ws_size,
                              hipStream_t stream) {
    const float* x   = (const float*)d_in[0];
    const int*   ei  = (const int*)d_in[1];
    const int*   bat = (const int*)d_in[2];
    const float* W1  = (const float*)d_in[3];
    const float* b1  = (const float*)d_in[4];
    const float* g1  = (const float*)d_in[5];
    const float* be1 = (const float*)d_in[6];
    const float* m1  = (const float*)d_in[7];
    const float* v1  = (const float*)d_in[8];
    const float* W2  = (const float*)d_in[9];
    const float* b2  = (const float*)d_in[10];
    const float* g2  = (const float*)d_in[11];
    const float* be2 = (const float*)d_in[12];
    const float* m2  = (const float*)d_in[13];
    const float* v2  = (const float*)d_in[14];
    const float* W3  = (const float*)d_in[15];
    const float* b3  = (const float*)d_in[16];
    const float* g3  = (const float*)d_in[17];
    const float* be3 = (const float*)d_in[18];
    const float* m3  = (const float*)d_in[19];
    const float* v3  = (const float*)d_in[20];
    const float* Wl  = (const float*)d_in[21];
    const float* bl  = (const float*)d_in[22];
    float* out = (float*)d_out;

    const int* srcp = ei;        // edge_index[0]
    const int* dstp = ei + NE;   // edge_index[1]

    // ---- workspace layout ----
    char* ws = (char*)d_ws;
    size_t off = 0;
    auto alloc = [&](size_t bytes) { char* p = ws + off; off += (bytes + 255) & ~255ULL; return p; };
    float*  dinv     = (float*) alloc(NN * 4);
    int*    rs       = (int*)   alloc((NN + 1) * 4);
    int*    L        = (int*)   alloc((size_t)NBIN * NBLK_BIN * 4);   // block-bin table, 153 KB
    int*    bin_ebase= (int*)   alloc((NBIN + 1) * 4);
    uint*   bpack    = (uint*)  alloc((size_t)NE * 4);   // 6.4 MB (bin-grouped edges)
    int*    csr      = (int*)   alloc((size_t)NE * 4);   // 6.4 MB
    float*  scale1 = (float*) alloc(HD * 4);
    float*  shift1 = (float*) alloc(HD * 4);
    float*  scale2 = (float*) alloc(HD * 4);
    float*  shift2 = (float*) alloc(HD * 4);
    float*  scale3 = (float*) alloc(HD * 4);
    float*  shift3 = (float*) alloc(HD * 4);
    float*  invcnt = (float*) alloc(NG * 4);
    float*  out2d  = (float*) alloc(NG * 8 * 4);
    ushort* Wt1    = (ushort*)alloc(128 * 128 * 2);    // 32 KB
    ushort* Wt2    = (ushort*)alloc(128 * 128 * 2);
    ushort* Wt3    = (ushort*)alloc(128 * 128 * 2);
    ushort* hs     = (ushort*)alloc((size_t)NN * HD * 2);   // 25.6 MB
    ushort* xbuf   = (ushort*)alloc((size_t)NN * HD * 2);   // 25.6 MB

    const int gath_grid = NN / 4;               // 25000 (one wave per node, exact)

    // ---- prep: W transpose + BN affine + graph inv-counts (one launch) ----
    k_prep_all<<<197, 256, 0, stream>>>(W1, W2, W3, Wt1, Wt2, Wt3,
                                        b1, g1, be1, m1, v1, b2, g2, be2, m2, v2,
                                        b3, g3, be3, m3, v3,
                                        scale1, shift1, scale2, shift2, scale3, shift3,
                                        bat, invcnt, out2d);

    // ---- fused: GEMM1 (unscaled) || bin histogram (LDS only) ----
    k_fused1<<<GEMM_BLOCKS + NBLK_BIN, 256, 0, stream>>>(x, Wt1, hs, dstp, L);

    // ---- CSR build: scan table, bin-scatter, per-bin CSR (+rs, dinv) ----
    k_binscan<<<1, 512, 0, stream>>>(L, bin_ebase, rs);
    k_binscatter<<<NBLK_BIN, 256, 0, stream>>>(srcp, dstp, L, bpack);
    k_bincsr<<<NBIN, 256, 0, stream>>>(bpack, bin_ebase, rs, dinv, csr);

    // ---- layer 1 gather (applies dinv[s] and dinv[d]) ----
    k_gather_w<true, false><<<gath_grid, 256, 0, stream>>>(
        hs, rs, csr, dinv, scale1, shift1, xbuf, nullptr, nullptr, nullptr, nullptr);
    // ---- layer 2 ----
    k_gemm_l23<<<GEMM_BLOCKS, 256, 0, stream>>>(xbuf, Wt2, dinv, hs);
    k_gather_w<false, false><<<gath_grid, 256, 0, stream>>>(
        hs, rs, csr, dinv, scale2, shift2, xbuf, nullptr, nullptr, nullptr, nullptr);
    // ---- layer 3: gather + pool + final-linear fused ----
    k_gemm_l23<<<GEMM_BLOCKS, 256, 0, stream>>>(xbuf, Wt3, dinv, hs);
    k_gather_w<false, true><<<gath_grid, 256, 0, stream>>>(
        hs, rs, csr, dinv, scale3, shift3, nullptr, bat, invcnt, Wl, out2d);

    // ---- finalize ----
    k_final<<<2, 256, 0, stream>>>(out2d, bl, out);
}